// Round 15
// baseline (124.742 us; speedup 1.0000x reference)
//
#include <hip/hip_runtime.h>

// out = 0.5 * sum_over_pooled( maxpool4( x @ W^T + b ) )  -> (batch,) fp32
// x: (M=4096, K=2048) f32, W: (N=4096, K=2048) f32, b: (N,) f32, out: (M,) f32
// Strategy: cvt to bf16 in ws (also zeroes out); 256x256 BK=64 8-wave GEMM
// using mfma_f32_32x32x16_bf16 (higher ceiling, half the MFMA issues) with a
// CHUNK-ROTATED XOR swizzle fixing R6's 4-way conflict:
//   byte(r,q) = (r>>3)*1024 + (r&7)*128 + sigma*16,
//   sigma = ((q ^ (r&7)) + 2*((r>>3)&3)) & 7
// -> every aligned 8-lane group of a 32-row fragment read covers all 8
//    bank-quads. Staging stays linear (global_load_lds); per-chunk inverse
//    source permutation q_src = (((l&7)-2*(c&3))&7)^(l>>3).
// R14 schedule: 1 barrier/phase, quadrants 00->01->11->10, b0 held P1->P4,
// b1 held P2->P3, counted vmcnt(6)/tile, setprio. Fused pool epilogue.

typedef float  f32x16  __attribute__((ext_vector_type(16)));
typedef short  bf16x8  __attribute__((ext_vector_type(8)));
typedef short  short4v __attribute__((ext_vector_type(4)));

__device__ __forceinline__ short f2bf(float f) {
    union { float f; unsigned u; } v; v.f = f;
    unsigned r = v.u + 0x7FFFu + ((v.u >> 16) & 1u);  // round-to-nearest-even
    return (short)(r >> 16);
}

__global__ void cvt_kernel(const float* __restrict__ x, const float* __restrict__ w,
                           short* __restrict__ out, long nx, long nw,
                           float* __restrict__ zout, int zn) {
    long stride = (long)gridDim.x * blockDim.x;
    long tid0   = (long)blockIdx.x * blockDim.x + threadIdx.x;
    // zero the output vector (atomics accumulate into it every graph replay)
    for (long i = tid0; i < zn; i += stride) zout[i] = 0.f;
    long total4 = (nx + nw) >> 2;
    for (long i = tid0; i < total4; i += stride) {
        long e = i << 2;
        const float* src = (e < nx) ? (x + e) : (w + (e - nx));
        float4 v = *(const float4*)src;
        short4v s = { f2bf(v.x), f2bf(v.y), f2bf(v.z), f2bf(v.w) };
        *(short4v*)(out + e) = s;
    }
}

#define GLL(gp, ldsp)                                                          \
    __builtin_amdgcn_global_load_lds(                                          \
        (const __attribute__((address_space(1))) unsigned int*)(gp),           \
        (__attribute__((address_space(3))) unsigned int*)(ldsp), 16, 0, 0)

__global__ __launch_bounds__(512, 1) void gemm_pool_kernel(
    const short* __restrict__ X, const short* __restrict__ W,
    const float* __restrict__ bias, float* __restrict__ out, int K)
{
    __shared__ short As[32768];   // 2 bufs x (256 rows x 64 k) = 64 KB
    __shared__ short Bs[32768];   // 64 KB

    const int tid  = threadIdx.x;
    const int lane = tid & 63;
    const int wid  = tid >> 6;     // 0..7
    const int wr   = wid >> 2;     // 0..1  (wave rows: 128 each)
    const int wc   = wid & 3;      // 0..3  (wave cols: 64 each)
    const int lo32 = lane & 31;    // 32x32 frag row/col
    const int hi32 = lane >> 5;    // 32x32 frag k-half

    // XCD-aware bijective block swizzle (nwg = 256, divisible by 8).
    const int nwg  = gridDim.x * gridDim.y;
    const int bid  = blockIdx.y * gridDim.x + blockIdx.x;
    const int wgid = (bid & 7) * (nwg >> 3) + (bid >> 3);
    const int brow = (wgid / gridDim.x) * 256;
    const int bcol = (wgid % gridDim.x) * 256;
    const int nk   = K >> 6;       // BK=64 tiles; requires nk even, >= 4

    // ---- fragment ds_read byte offsets (per k-step ks, q = 2*ks + hi32) ----
    // sigma(q) = ((q ^ (lane&7)) + 2*(((lane&31)>>3)&3)) & 7
    int offA[4], offB[4];
    {
        const int rot = 2 * (((lane & 31) >> 3) & 3);
        const int cbA = (wr * 16 + ((lane & 31) >> 3)) * 1024 + (lane & 7) * 128;
        const int cbB = (wc * 8  + ((lane & 31) >> 3)) * 1024 + (lane & 7) * 128;
#pragma unroll
        for (int ks = 0; ks < 4; ++ks) {
            const int q  = 2 * ks + hi32;
            const int sg = (((q ^ (lane & 7)) + rot) & 7) * 16;
            offA[ks] = cbA + sg;
            offB[ks] = cbB + sg;
        }
    }
    const char* Ab8 = (const char*)As;
    const char* Bb8 = (const char*)Bs;

    // ---- staging chunk ids and running global pointers (kt = 0) ----
    const int idx0 = wid * 2, idx1 = wid * 2 + 1;
    const int cA00 = (idx0 & 7) + ((idx0 >> 3) << 4), cA10 = (idx1 & 7) + ((idx1 >> 3) << 4);
    const int cA01 = cA00 + 8,                         cA11 = cA10 + 8;
    const int cB00 = ((idx0 >> 2) << 3) + (idx0 & 3),  cB10 = ((idx1 >> 2) << 3) + (idx1 & 3);
    const int cB01 = cB00 + 4,                         cB11 = cB10 + 4;
    const int grow = lane >> 3;
    // per-chunk inverse source permutation (short offset = q_src*8)
#define QSRC(c) ((((((lane & 7) - 2 * ((c) & 3)) & 7) ^ (lane >> 3))) * 8)

    const short* pA00 = X + (size_t)(brow + cA00 * 8 + grow) * K + QSRC(cA00);
    const short* pA10 = X + (size_t)(brow + cA10 * 8 + grow) * K + QSRC(cA10);
    const short* pA01 = X + (size_t)(brow + cA01 * 8 + grow) * K + QSRC(cA01);
    const short* pA11 = X + (size_t)(brow + cA11 * 8 + grow) * K + QSRC(cA11);
    const short* pB00 = W + (size_t)(bcol + cB00 * 8 + grow) * K + QSRC(cB00);
    const short* pB10 = W + (size_t)(bcol + cB10 * 8 + grow) * K + QSRC(cB10);
    const short* pB01 = W + (size_t)(bcol + cB01 * 8 + grow) * K + QSRC(cB01);
    const short* pB11 = W + (size_t)(bcol + cB11 * 8 + grow) * K + QSRC(cB11);
#undef QSRC

    f32x16 acc[4][2] = {};         // [m-block of 32][n-block of 32]
    bf16x8 a[2][4], b0[4], b1[4];  // a: 2 m-blocks x 4 ks (one m-half)

    // ---- prologue: tile 0 fully + {A0,B1,A1}(1) ----
    GLL(pA00, As + cA00 * 512); GLL(pA10, As + cA10 * 512);               // A0(0)
    GLL(pB00, Bs + cB00 * 512); GLL(pB10, Bs + cB10 * 512);               // B0(0)
    GLL(pB01, Bs + cB01 * 512); GLL(pB11, Bs + cB11 * 512);               // B1(0)
    GLL(pA01, As + cA01 * 512); GLL(pA11, As + cA11 * 512);               // A1(0)
    GLL(pA00 + 64, As + 16384 + cA00 * 512); GLL(pA10 + 64, As + 16384 + cA10 * 512); // A0(1)
    GLL(pB01 + 64, Bs + 16384 + cB01 * 512); GLL(pB11 + 64, Bs + 16384 + cB11 * 512); // B1(1)
    GLL(pA01 + 64, As + 16384 + cA01 * 512); GLL(pA11 + 64, As + 16384 + cA11 * 512); // A1(1)
    pA00 += 128; pA10 += 128; pA01 += 128; pA11 += 128;
    pB00 += 128; pB10 += 128; pB01 += 128; pB11 += 128;   // now at kt = 2
    asm volatile("s_waitcnt vmcnt(6)" ::: "memory");       // tile-0 complete

    // Phase = {barrier; ds_reads (b first); stage; setprio; MFMA}.
    // Quadrants (m-half, n-block): (0,0) (0,1) (1,1) (1,0); b0 held P1->P4,
    // b1 held P2->P3; P4 reads nothing. Same WAR/RAW ledger as R10-R14.
#define TILE_BODY(T, BUF)                                                          \
    {                                                                              \
        /* P1: reads b0(4)+a-half0(8); stage B0(T+1)->other buf; MFMA (0..1,0) */  \
        __builtin_amdgcn_s_barrier();                                              \
        _Pragma("unroll")                                                          \
        for (int ks = 0; ks < 4; ++ks)                                             \
            b0[ks] = *(const bf16x8*)(Bb8 + (BUF)*32768 + offB[ks]);               \
        _Pragma("unroll")                                                          \
        for (int mq = 0; mq < 2; ++mq)                                             \
            _Pragma("unroll")                                                      \
            for (int ks = 0; ks < 4; ++ks)                                         \
                a[mq][ks] = *(const bf16x8*)(Ab8 + (BUF)*32768 + offA[ks] + mq*4096); \
        if ((T) + 1 < nk) {                                                        \
            GLL(pB00 - 64, Bs + (1-(BUF))*16384 + cB00*512);                       \
            GLL(pB10 - 64, Bs + (1-(BUF))*16384 + cB10*512);                       \
        }                                                                          \
        __builtin_amdgcn_s_setprio(1);                                             \
        _Pragma("unroll")                                                          \
        for (int ks = 0; ks < 4; ++ks) {                                           \
            acc[0][0] = __builtin_amdgcn_mfma_f32_32x32x16_bf16(a[0][ks], b0[ks], acc[0][0], 0, 0, 0); \
            acc[1][0] = __builtin_amdgcn_mfma_f32_32x32x16_bf16(a[1][ks], b0[ks], acc[1][0], 0, 0, 0); \
        }                                                                          \
        __builtin_amdgcn_s_setprio(0);                                             \
        /* P2: reads b1(4); stage A0(T+2)->same buf; MFMA (0..1,1) */              \
        __builtin_amdgcn_s_barrier();                                              \
        _Pragma("unroll")                                                          \
        for (int ks = 0; ks < 4; ++ks)                                             \
            b1[ks] = *(const bf16x8*)(Bb8 + (BUF)*32768 + offB[ks] + 4096);        \
        if ((T) + 2 < nk) {                                                        \
            GLL(pA00, As + (BUF)*16384 + cA00*512);                                \
            GLL(pA10, As + (BUF)*16384 + cA10*512);                                \
        }                                                                          \
        __builtin_amdgcn_s_setprio(1);                                             \
        _Pragma("unroll")                                                          \
        for (int ks = 0; ks < 4; ++ks) {                                           \
            acc[0][1] = __builtin_amdgcn_mfma_f32_32x32x16_bf16(a[0][ks], b1[ks], acc[0][1], 0, 0, 0); \
            acc[1][1] = __builtin_amdgcn_mfma_f32_32x32x16_bf16(a[1][ks], b1[ks], acc[1][1], 0, 0, 0); \
        }                                                                          \
        __builtin_amdgcn_s_setprio(0);                                             \
        /* P3: reads a-half1(8) [+8192B]; stage B1(T+2); MFMA (2..3,1) */          \
        __builtin_amdgcn_s_barrier();                                              \
        _Pragma("unroll")                                                          \
        for (int mq = 0; mq < 2; ++mq)                                             \
            _Pragma("unroll")                                                      \
            for (int ks = 0; ks < 4; ++ks)                                         \
                a[mq][ks] = *(const bf16x8*)(Ab8 + (BUF)*32768 + offA[ks] + 8192 + mq*4096); \
        if ((T) + 2 < nk) {                                                        \
            GLL(pB01, Bs + (BUF)*16384 + cB01*512);                                \
            GLL(pB11, Bs + (BUF)*16384 + cB11*512);                                \
        }                                                                          \
        __builtin_amdgcn_s_setprio(1);                                             \
        _Pragma("unroll")                                                          \
        for (int ks = 0; ks < 4; ++ks) {                                           \
            acc[2][1] = __builtin_amdgcn_mfma_f32_32x32x16_bf16(a[0][ks], b1[ks], acc[2][1], 0, 0, 0); \
            acc[3][1] = __builtin_amdgcn_mfma_f32_32x32x16_bf16(a[1][ks], b1[ks], acc[3][1], 0, 0, 0); \
        }                                                                          \
        __builtin_amdgcn_s_setprio(0);                                             \
        /* P4: no reads; stage A1(T+2); MFMA (2..3,0) [b0 held]; boundary */       \
        __builtin_amdgcn_s_barrier();                                              \
        if ((T) + 2 < nk) {                                                        \
            GLL(pA01, As + (BUF)*16384 + cA01*512);                                \
            GLL(pA11, As + (BUF)*16384 + cA11*512);                                \
        }                                                                          \
        __builtin_amdgcn_s_setprio(1);                                             \
        _Pragma("unroll")                                                          \
        for (int ks = 0; ks < 4; ++ks) {                                           \
            acc[2][0] = __builtin_amdgcn_mfma_f32_32x32x16_bf16(a[0][ks], b0[ks], acc[2][0], 0, 0, 0); \
            acc[3][0] = __builtin_amdgcn_mfma_f32_32x32x16_bf16(a[1][ks], b0[ks], acc[3][0], 0, 0, 0); \
        }                                                                          \
        __builtin_amdgcn_s_setprio(0);                                             \
        if ((T) == nk - 2)      asm volatile("s_waitcnt vmcnt(0)" ::: "memory");   \
        else if ((T) < nk - 2)  asm volatile("s_waitcnt vmcnt(6)" ::: "memory");   \
        pA00 += 64; pA10 += 64; pA01 += 64; pA11 += 64;                            \
        pB00 += 64; pB10 += 64; pB01 += 64; pB11 += 64;                            \
    }

    for (int t = 0; t < nk; t += 2) {
        TILE_BODY(t, 0);
        TILE_BODY(t + 1, 1);
    }
#undef TILE_BODY

    // Epilogue: bias + maxpool4(cols) + rowsum, fused.
    // 32x32 C/D mapping: col = lane&31, row = (r&3)+8*(r>>2)+4*(lane>>5)
    // [m74/m101-verified; validated end-to-end in R6].
    float bias_n[2];
#pragma unroll
    for (int nn = 0; nn < 2; ++nn)
        bias_n[nn] = bias[bcol + wc * 64 + nn * 32 + lo32];

#pragma unroll
    for (int mq = 0; mq < 4; ++mq) {
#pragma unroll
        for (int r = 0; r < 16; ++r) {
            float part = 0.f;
#pragma unroll
            for (int nn = 0; nn < 2; ++nn) {
                float v = acc[mq][nn][r] + bias_n[nn];
                v = fmaxf(v, __shfl_xor(v, 1));   // pool across col bit 0
                v = fmaxf(v, __shfl_xor(v, 2));   // pool across col bit 1
                part += v;                        // lane holds pooled[(lo32>>2)]
            }
            part += __shfl_xor(part, 4);          // sum the 8 pool groups
            part += __shfl_xor(part, 8);
            part += __shfl_xor(part, 16);
            if (lo32 == 0)
                atomicAdd(&out[brow + wr * 128 + mq * 32 +
                               (r & 3) + 8 * (r >> 2) + 4 * hi32], part * 0.5f);
        }
    }
}

extern "C" void kernel_launch(void* const* d_in, const int* in_sizes, int n_in,
                              void* d_out, int out_size, void* d_ws, size_t ws_size,
                              hipStream_t stream) {
    const float* x = (const float*)d_in[0];
    const float* W = (const float*)d_in[1];
    const float* b = (const float*)d_in[2];
    float* out = (float*)d_out;

    const int N = in_sizes[2];             // out_f = 4096
    const int K = in_sizes[1] / N;         // in_f  = 2048
    const int M = in_sizes[0] / K;         // batch = 4096

    short* xb = (short*)d_ws;
    short* wb = xb + in_sizes[0];
    // cvt also zeroes `out` (atomics accumulate across graph replays).
    cvt_kernel<<<2048, 256, 0, stream>>>(x, W, (short*)d_ws,
                                         (long)in_sizes[0], (long)in_sizes[1],
                                         out, out_size);

    dim3 grid(N / 256, M / 256);           // 256 blocks
    gemm_pool_kernel<<<grid, 512, 0, stream>>>(xb, wb, b, out, K);
}

// Round 16
// 86.003 us; speedup vs baseline: 1.4504x; 1.4504x over previous
//
#include <hip/hip_runtime.h>

// out = 0.5 * sum_over_pooled( maxpool4( x @ W^T + b ) )  -> (batch,) fp32
// x: (M=4096, K=2048) f32, W: (N=4096, K=2048) f32, b: (N,) f32, out: (M,) f32
// FINAL (R14 config, best measured 84.6us): cvt to bf16 in ws (also zeroes
// out); 256x256 BK=64 8-wave MFMA GEMM, 16x16x32 shape (the only shape that
// measures 0 bank conflicts under the XOR swizzle). Phase = {barrier;
// ds_reads (b first); stage via global_load_lds w=16; setprio; MFMA};
// quadrants 00->01->11->10 with b0 held P1->P4, b1 held P2->P3; counted
// vmcnt(6) per tile. Fused bias+maxpool4+rowsum epilogue with atomicAdd.

typedef float  f32x4   __attribute__((ext_vector_type(4)));
typedef short  bf16x8  __attribute__((ext_vector_type(8)));
typedef short  short4v __attribute__((ext_vector_type(4)));

__device__ __forceinline__ short f2bf(float f) {
    union { float f; unsigned u; } v; v.f = f;
    unsigned r = v.u + 0x7FFFu + ((v.u >> 16) & 1u);  // round-to-nearest-even
    return (short)(r >> 16);
}

__global__ void cvt_kernel(const float* __restrict__ x, const float* __restrict__ w,
                           short* __restrict__ out, long nx, long nw,
                           float* __restrict__ zout, int zn) {
    long stride = (long)gridDim.x * blockDim.x;
    long tid0   = (long)blockIdx.x * blockDim.x + threadIdx.x;
    // zero the output vector (atomics accumulate into it every graph replay)
    for (long i = tid0; i < zn; i += stride) zout[i] = 0.f;
    long total4 = (nx + nw) >> 2;
    for (long i = tid0; i < total4; i += stride) {
        long e = i << 2;
        const float* src = (e < nx) ? (x + e) : (w + (e - nx));
        float4 v = *(const float4*)src;
        short4v s = { f2bf(v.x), f2bf(v.y), f2bf(v.z), f2bf(v.w) };
        *(short4v*)(out + e) = s;
    }
}

// LDS layout per 32KB buffer: row r (0..255), k-slice q (0..7 16B slices):
// short-offset = (r>>3)*512 + (r&7)*64 + (q^(r&7))*8.  Conflict-free
// ds_read_b128 (measured: SQ_LDS_BANK_CONFLICT=0, R9-R14). Staging linear
// per chunk (8 rows = 1KB = one wave-wide global_load_lds); global source
// applies the inverse swizzle: row = c*8 + (l>>3), q = (l&7)^(l>>3).
// Byte offsets: mm/nn +16 rows = +2048 B; b-half +32 rows = +4096 B;
// a-half +64 rows = +8192 B; buffer stride 32768 B.

#define GLL(gp, ldsp)                                                          \
    __builtin_amdgcn_global_load_lds(                                          \
        (const __attribute__((address_space(1))) unsigned int*)(gp),           \
        (__attribute__((address_space(3))) unsigned int*)(ldsp), 16, 0, 0)

__global__ __launch_bounds__(512, 1) void gemm_pool_kernel(
    const short* __restrict__ X, const short* __restrict__ W,
    const float* __restrict__ bias, float* __restrict__ out, int K)
{
    __shared__ short As[32768];   // 2 bufs x (256 rows x 64 k) = 64 KB
    __shared__ short Bs[32768];   // 64 KB

    const int tid  = threadIdx.x;
    const int lane = tid & 63;
    const int wid  = tid >> 6;     // 0..7
    const int wr   = wid >> 2;     // 0..1  (wave rows: 128 each)
    const int wc   = wid & 3;      // 0..3  (wave cols: 64 each)
    const int hi   = lane >> 4;    // frag k-slice part
    const int lo   = lane & 15;    // frag row part

    // XCD-aware bijective block swizzle (nwg = 256, divisible by 8).
    const int nwg  = gridDim.x * gridDim.y;
    const int bid  = blockIdx.y * gridDim.x + blockIdx.x;
    const int wgid = (bid & 7) * (nwg >> 3) + (bid >> 3);
    const int brow = (wgid / gridDim.x) * 256;
    const int bcol = (wgid % gridDim.x) * 256;
    const int nk   = K >> 6;       // BK=64 tiles; requires nk even, >= 4

    // ---- thread-constant ds_read bases (all loop reads = base + imm) ----
    const int slot0 = hi ^ (lo & 7);
    const int slot1 = (4 + hi) ^ (lo & 7);
    const char* baseA0 = (const char*)As + (((wr * 16 + (lo >> 3)) * 512 + (lo & 7) * 64 + slot0 * 8) << 1);
    const char* baseA1 = (const char*)As + (((wr * 16 + (lo >> 3)) * 512 + (lo & 7) * 64 + slot1 * 8) << 1);
    const char* baseB0 = (const char*)Bs + (((wc * 8  + (lo >> 3)) * 512 + (lo & 7) * 64 + slot0 * 8) << 1);
    const char* baseB1 = (const char*)Bs + (((wc * 8  + (lo >> 3)) * 512 + (lo & 7) * 64 + slot1 * 8) << 1);

    // ---- staging chunk ids and running global pointers (kt = 0) ----
    const int idx0 = wid * 2, idx1 = wid * 2 + 1;
    const int cA00 = (idx0 & 7) + ((idx0 >> 3) << 4), cA10 = (idx1 & 7) + ((idx1 >> 3) << 4);
    const int cA01 = cA00 + 8,                         cA11 = cA10 + 8;
    const int cB00 = ((idx0 >> 2) << 3) + (idx0 & 3),  cB10 = ((idx1 >> 2) << 3) + (idx1 & 3);
    const int cB01 = cB00 + 4,                         cB11 = cB10 + 4;
    const int grow = lane >> 3;
    const int gq8  = ((lane & 7) ^ (lane >> 3)) * 8;

    const short* pA00 = X + (size_t)(brow + cA00 * 8 + grow) * K + gq8;
    const short* pA10 = X + (size_t)(brow + cA10 * 8 + grow) * K + gq8;
    const short* pA01 = X + (size_t)(brow + cA01 * 8 + grow) * K + gq8;
    const short* pA11 = X + (size_t)(brow + cA11 * 8 + grow) * K + gq8;
    const short* pB00 = W + (size_t)(bcol + cB00 * 8 + grow) * K + gq8;
    const short* pB10 = W + (size_t)(bcol + cB10 * 8 + grow) * K + gq8;
    const short* pB01 = W + (size_t)(bcol + cB01 * 8 + grow) * K + gq8;
    const short* pB11 = W + (size_t)(bcol + cB11 * 8 + grow) * K + gq8;

    f32x4 acc[8][4] = {};
    bf16x8 a[4][2], b0[2][2], b1[2][2];

    // ---- prologue: tile 0 fully + {A0,B1,A1}(1) ----
    GLL(pA00, As + cA00 * 512); GLL(pA10, As + cA10 * 512);               // A0(0)
    GLL(pB00, Bs + cB00 * 512); GLL(pB10, Bs + cB10 * 512);               // B0(0)
    GLL(pB01, Bs + cB01 * 512); GLL(pB11, Bs + cB11 * 512);               // B1(0)
    GLL(pA01, As + cA01 * 512); GLL(pA11, As + cA11 * 512);               // A1(0)
    GLL(pA00 + 64, As + 16384 + cA00 * 512); GLL(pA10 + 64, As + 16384 + cA10 * 512); // A0(1)
    GLL(pB01 + 64, Bs + 16384 + cB01 * 512); GLL(pB11 + 64, Bs + 16384 + cB11 * 512); // B1(1)
    GLL(pA01 + 64, As + 16384 + cA01 * 512); GLL(pA11 + 64, As + 16384 + cA11 * 512); // A1(1)
    pA00 += 128; pA10 += 128; pA01 += 128; pA11 += 128;
    pB00 += 128; pB10 += 128; pB01 += 128; pB11 += 128;   // now at kt = 2
    asm volatile("s_waitcnt vmcnt(6)" ::: "memory");       // tile-0 complete

    // Phase = {barrier; ds_reads (b first); stage; setprio; MFMA}.
    // No explicit lgkm drain: MFMA data deps give counted lgkm waits; all
    // reads are consumed before the next barrier (WAR-safe). Quadrants
    // 00,01,11,10 with b0 held P1->P4 and b1 held P2->P3 (P4 reads nothing).
#define TILE_BODY(T, BUF)                                                          \
    {                                                                              \
        /* P1: reads b0(4)+a0(8); stage B0(T+1)->other buf; MFMA (0,0) */          \
        __builtin_amdgcn_s_barrier();                                              \
        _Pragma("unroll")                                                          \
        for (int nn = 0; nn < 2; ++nn) {                                           \
            b0[nn][0] = *(const bf16x8*)(baseB0 + (BUF)*32768 + nn*2048);          \
            b0[nn][1] = *(const bf16x8*)(baseB1 + (BUF)*32768 + nn*2048);          \
        }                                                                          \
        _Pragma("unroll")                                                          \
        for (int mm = 0; mm < 4; ++mm) {                                           \
            a[mm][0] = *(const bf16x8*)(baseA0 + (BUF)*32768 + mm*2048);           \
            a[mm][1] = *(const bf16x8*)(baseA1 + (BUF)*32768 + mm*2048);           \
        }                                                                          \
        if ((T) + 1 < nk) {                                                        \
            GLL(pB00 - 64, Bs + (1-(BUF))*16384 + cB00*512);                       \
            GLL(pB10 - 64, Bs + (1-(BUF))*16384 + cB10*512);                       \
        }                                                                          \
        __builtin_amdgcn_s_setprio(1);                                             \
        _Pragma("unroll")                                                          \
        for (int mm = 0; mm < 4; ++mm)                                             \
            _Pragma("unroll")                                                      \
            for (int nn = 0; nn < 2; ++nn)                                         \
                _Pragma("unroll")                                                  \
                for (int kk = 0; kk < 2; ++kk)                                     \
                    acc[mm][nn] = __builtin_amdgcn_mfma_f32_16x16x32_bf16(         \
                        a[mm][kk], b0[nn][kk], acc[mm][nn], 0, 0, 0);              \
        __builtin_amdgcn_s_setprio(0);                                             \
        /* P2: reads b1(4); stage A0(T+2)->same buf; MFMA (0,1) */                 \
        __builtin_amdgcn_s_barrier();                                              \
        _Pragma("unroll")                                                          \
        for (int nn = 0; nn < 2; ++nn) {                                           \
            b1[nn][0] = *(const bf16x8*)(baseB0 + (BUF)*32768 + nn*2048 + 4096);   \
            b1[nn][1] = *(const bf16x8*)(baseB1 + (BUF)*32768 + nn*2048 + 4096);   \
        }                                                                          \
        if ((T) + 2 < nk) {                                                        \
            GLL(pA00, As + (BUF)*16384 + cA00*512);                                \
            GLL(pA10, As + (BUF)*16384 + cA10*512);                                \
        }                                                                          \
        __builtin_amdgcn_s_setprio(1);                                             \
        _Pragma("unroll")                                                          \
        for (int mm = 0; mm < 4; ++mm)                                             \
            _Pragma("unroll")                                                      \
            for (int nn = 0; nn < 2; ++nn)                                         \
                _Pragma("unroll")                                                  \
                for (int kk = 0; kk < 2; ++kk)                                     \
                    acc[mm][2+nn] = __builtin_amdgcn_mfma_f32_16x16x32_bf16(       \
                        a[mm][kk], b1[nn][kk], acc[mm][2+nn], 0, 0, 0);            \
        __builtin_amdgcn_s_setprio(0);                                             \
        /* P3: reads a1(8) [+8192B]; stage B1(T+2); MFMA (1,1) [b1 held] */        \
        __builtin_amdgcn_s_barrier();                                              \
        _Pragma("unroll")                                                          \
        for (int mm = 0; mm < 4; ++mm) {                                           \
            a[mm][0] = *(const bf16x8*)(baseA0 + (BUF)*32768 + mm*2048 + 8192);    \
            a[mm][1] = *(const bf16x8*)(baseA1 + (BUF)*32768 + mm*2048 + 8192);    \
        }                                                                          \
        if ((T) + 2 < nk) {                                                        \
            GLL(pB01, Bs + (BUF)*16384 + cB01*512);                                \
            GLL(pB11, Bs + (BUF)*16384 + cB11*512);                                \
        }                                                                          \
        __builtin_amdgcn_s_setprio(1);                                             \
        _Pragma("unroll")                                                          \
        for (int mm = 0; mm < 4; ++mm)                                             \
            _Pragma("unroll")                                                      \
            for (int nn = 0; nn < 2; ++nn)                                         \
                _Pragma("unroll")                                                  \
                for (int kk = 0; kk < 2; ++kk)                                     \
                    acc[4+mm][2+nn] = __builtin_amdgcn_mfma_f32_16x16x32_bf16(     \
                        a[mm][kk], b1[nn][kk], acc[4+mm][2+nn], 0, 0, 0);          \
        __builtin_amdgcn_s_setprio(0);                                             \
        /* P4: no reads; stage A1(T+2); MFMA (1,0) [b0 held]; boundary */          \
        __builtin_amdgcn_s_barrier();                                              \
        if ((T) + 2 < nk) {                                                        \
            GLL(pA01, As + (BUF)*16384 + cA01*512);                                \
            GLL(pA11, As + (BUF)*16384 + cA11*512);                                \
        }                                                                          \
        __builtin_amdgcn_s_setprio(1);                                             \
        _Pragma("unroll")                                                          \
        for (int mm = 0; mm < 4; ++mm)                                             \
            _Pragma("unroll")                                                      \
            for (int nn = 0; nn < 2; ++nn)                                         \
                _Pragma("unroll")                                                  \
                for (int kk = 0; kk < 2; ++kk)                                     \
                    acc[4+mm][nn] = __builtin_amdgcn_mfma_f32_16x16x32_bf16(       \
                        a[mm][kk], b0[nn][kk], acc[4+mm][nn], 0, 0, 0);            \
        __builtin_amdgcn_s_setprio(0);                                             \
        if ((T) == nk - 2)      asm volatile("s_waitcnt vmcnt(0)" ::: "memory");   \
        else if ((T) < nk - 2)  asm volatile("s_waitcnt vmcnt(6)" ::: "memory");   \
        pA00 += 64; pA10 += 64; pA01 += 64; pA11 += 64;                            \
        pB00 += 64; pB10 += 64; pB01 += 64; pB11 += 64;                            \
    }

    for (int t = 0; t < nk; t += 2) {
        TILE_BODY(t, 0);
        TILE_BODY(t + 1, 1);
    }
#undef TILE_BODY

    // Epilogue: bias + maxpool4(cols) + rowsum, fused.
    // C/D frag mapping: col = lane&15, row = (lane>>4)*4 + reg  [m89-verified]
    float bias_n[4];
#pragma unroll
    for (int nn = 0; nn < 4; ++nn)
        bias_n[nn] = bias[bcol + wc * 64 + nn * 16 + lo];

#pragma unroll
    for (int mm = 0; mm < 8; ++mm) {
#pragma unroll
        for (int j = 0; j < 4; ++j) {
            float part = 0.f;
#pragma unroll
            for (int nn = 0; nn < 4; ++nn) {
                float v = acc[mm][nn][j] + bias_n[nn];
                v = fmaxf(v, __shfl_xor(v, 1));   // pool across col bit 0
                v = fmaxf(v, __shfl_xor(v, 2));   // pool across col bit 1
                part += v;                        // lane holds pooled[(lo>>2)]
            }
            part += __shfl_xor(part, 4);          // sum the 4 pool groups
            part += __shfl_xor(part, 8);
            if (lo == 0)
                atomicAdd(&out[brow + wr * 128 + mm * 16 + hi * 4 + j], part * 0.5f);
        }
    }
}

extern "C" void kernel_launch(void* const* d_in, const int* in_sizes, int n_in,
                              void* d_out, int out_size, void* d_ws, size_t ws_size,
                              hipStream_t stream) {
    const float* x = (const float*)d_in[0];
    const float* W = (const float*)d_in[1];
    const float* b = (const float*)d_in[2];
    float* out = (float*)d_out;

    const int N = in_sizes[2];             // out_f = 4096
    const int K = in_sizes[1] / N;         // in_f  = 2048
    const int M = in_sizes[0] / K;         // batch = 4096

    short* xb = (short*)d_ws;
    short* wb = xb + in_sizes[0];
    // cvt also zeroes `out` (atomics accumulate across graph replays).
    cvt_kernel<<<2048, 256, 0, stream>>>(x, W, (short*)d_ws,
                                         (long)in_sizes[0], (long)in_sizes[1],
                                         out, out_size);

    dim3 grid(N / 256, M / 256);           // 256 blocks
    gemm_pool_kernel<<<grid, 512, 0, stream>>>(xb, wb, b, out, K);
}